// Round 12
// baseline (416.119 us; speedup 1.0000x reference)
//
#include <hip/hip_runtime.h>
#include <math.h>

// Negative L1 cdist: out[n,m] = -sum_d |x[n,d] - w[m,d]|
// N=8192, M=1024, D=64, fp32 in/out.
//
// R11 post-mortem: compiler's occupancy heuristic targets 64 arch VGPRs;
// wq[64] forced a scratch spill (FETCH 300 MB, 152us). R9's AGPR pathology
// = same root cause. Rule: keep live VGPRs <= ~56.
// R12: split-D structure, designed to FIT the 64-VGPR budget:
//   - per lane: wq4[8] (half w row, 32 regs) + acc[8] (NR=8) ~= 52 live
//   - two passes over d (half each), w half reloaded from L2 between passes
//   - x tile (8 rows, 2 KB) in LDS, broadcast ds_read_b128, one barrier
//   - lane <-> m: coalesced 1 KB/wave-row stores; single kernel, exact f32
// 8 waves/SIMD (compiler's preference now works FOR latency hiding).
// Floor: 2 VALU/elem = 13.7 us chip-wide; model ~14-15 us.

constexpr int Nn = 8192, Mm = 1024, Dd = 64;
constexpr int NR = 8;                      // n-rows per block

__global__ __launch_bounds__(256, 4) void cdist_l1_f32s_kernel(
    const float* __restrict__ x, const float* __restrict__ w,
    float* __restrict__ out)
{
    __shared__ float4 sx4[NR * 16];        // 8 rows x 64 f32 = 2 KB
    const int t  = threadIdx.x;
    const int m  = blockIdx.x * 256 + t;   // lane <-> m column
    const int n0 = blockIdx.y * NR;

    // ---- stage x tile: 128 float4 = 8 rows (threads 0..127) ----
    if (t < NR * 16) sx4[t] = ((const float4*)(x + (size_t)n0 * Dd))[t];

    float acc[NR];
#pragma unroll
    for (int i = 0; i < NR; ++i) acc[i] = 0.0f;

    const float4* wp = (const float4*)(w + (size_t)m * Dd);
    __syncthreads();                       // the only barrier

#pragma unroll 1                           // halves must SHARE wq4 registers
    for (int half = 0; half < 2; ++half) {
        // half w row: 8 float4 = 32 VGPRs (L2-resident reload)
        float4 wq4[8];
#pragma unroll
        for (int j = 0; j < 8; ++j) wq4[j] = wp[half * 8 + j];

#pragma unroll
        for (int i = 0; i < NR; ++i) {
            const float4* xr = &sx4[i * 16 + half * 8];  // 8x b128 broadcast
            float a0 = 0.0f, a1 = 0.0f;
#pragma unroll
            for (int j = 0; j < 8; ++j) {
                const float4 xv = xr[j];
                const float4 wv = wq4[j];
                a0 += fabsf(xv.x - wv.x);  // v_sub + v_add(|.| mod)
                a1 += fabsf(xv.y - wv.y);
                a0 += fabsf(xv.z - wv.z);
                a1 += fabsf(xv.w - wv.w);
            }
            acc[i] -= a0 + a1;             // one acc touch per (row, half)
        }
    }

    // ---- stores: 8 coalesced 1 KB wave-rows ----
#pragma unroll
    for (int i = 0; i < NR; ++i)
        out[(size_t)(n0 + i) * Mm + m] = acc[i];
}

extern "C" void kernel_launch(void* const* d_in, const int* in_sizes, int n_in,
                              void* d_out, int out_size, void* d_ws, size_t ws_size,
                              hipStream_t stream) {
    (void)in_sizes; (void)n_in; (void)out_size; (void)d_ws; (void)ws_size;
    const float* x = (const float*)d_in[0];   // [8192, 64] fp32
    const float* w = (const float*)d_in[1];   // [1024, 64] fp32
    float* out = (float*)d_out;               // [8192, 1024] fp32

    // (4, 1024) = 4096 blocks -> 16 blocks/CU over kernel, 8 waves/SIMD
    cdist_l1_f32s_kernel<<<dim3(Mm / 256, Nn / NR), dim3(256), 0, stream>>>(
        x, w, out);
}

// Round 13
// 210.720 us; speedup vs baseline: 1.9747x; 1.9747x over previous
//
#include <hip/hip_runtime.h>
#include <math.h>

// Negative L1 cdist: out[n,m] = -sum_d |x[n,d] - w[m,d]|
// N=8192, M=1024, D=64, fp32 in/out.
//
// R9/R11/R12 post-mortem (one mechanism): AMDGPU occupancy heuristic targets
// 8 waves/EU = 64 arch VGPRs when LDS is small, and SCRATCH-SPILLS per-lane
// arrays rather than allocating 128 regs at 4 waves/EU. __launch_bounds__
// only sets the min-occupancy cap; it doesn't lower the heuristic's target.
// R12's WRITE=1.18GB / R11's FETCH=300MB were pure spill traffic.
// R13: pin the occupancy window with amdgpu_waves_per_eu(4,4) -> register
// budget exactly 128, no incentive to squeeze. Structure = R11 (never
// actually falsified):
//   - lane <-> m: coalesced 1 KB/wave-row stores
//   - w row = wq[64] f32 in VGPRs (~85 live regs, fits 128)
//   - x tile (16 rows, 4 KB) in LDS, broadcast ds_read_b128, one barrier
//   - 4 independent acc chains, 2 f32 VALU/elem (sub + add with |.| mod)
// Floors: VALU 33k cy/CU = 13.7 us; LDS 8192 broadcast b128/CU ~ 33k cy,
// overlapped across 4 waves/EU. Model: 16-19 us.

constexpr int Nn = 8192, Mm = 1024, Dd = 64;
constexpr int NR = 16;                     // n-rows per block

__global__ __attribute__((amdgpu_flat_work_group_size(256, 256),
                          amdgpu_waves_per_eu(4, 4)))
void cdist_l1_f32p_kernel(
    const float* __restrict__ x, const float* __restrict__ w,
    float* __restrict__ out)
{
    __shared__ float4 sx4[NR * 16];        // 16 rows x 64 f32 = 4 KB
    const int t  = threadIdx.x;
    const int m  = blockIdx.x * 256 + t;   // lane <-> m column
    const int n0 = blockIdx.y * NR;

    // ---- stage x tile: 256 float4 = 16 rows, fully coalesced ----
    sx4[t] = ((const float4*)(x + (size_t)n0 * Dd))[t];

    // ---- w row -> 64 f32 in VGPRs ----
    float wq[Dd];
    {
        const float4* wp = (const float4*)(w + (size_t)m * Dd);
#pragma unroll
        for (int i = 0; i < 16; ++i) {
            const float4 v = wp[i];
            wq[4 * i + 0] = v.x;
            wq[4 * i + 1] = v.y;
            wq[4 * i + 2] = v.z;
            wq[4 * i + 3] = v.w;
        }
    }
    __syncthreads();                       // the only barrier

    for (int i = 0; i < NR; ++i) {
        const float4* xr = &sx4[i * 16];   // 16x ds_read_b128, broadcast
        float a0 = 0.0f, a1 = 0.0f, a2 = 0.0f, a3 = 0.0f;
#pragma unroll
        for (int j = 0; j < 16; ++j) {
            const float4 xv = xr[j];
            a0 += fabsf(xv.x - wq[4 * j + 0]);   // v_sub + v_add(|.| mod)
            a1 += fabsf(xv.y - wq[4 * j + 1]);
            a2 += fabsf(xv.z - wq[4 * j + 2]);
            a3 += fabsf(xv.w - wq[4 * j + 3]);
        }
        // coalesced: 1 KB contiguous per wave-row
        out[(size_t)(n0 + i) * Mm + m] = -((a0 + a1) + (a2 + a3));
    }
}

extern "C" void kernel_launch(void* const* d_in, const int* in_sizes, int n_in,
                              void* d_out, int out_size, void* d_ws, size_t ws_size,
                              hipStream_t stream) {
    (void)in_sizes; (void)n_in; (void)out_size; (void)d_ws; (void)ws_size;
    const float* x = (const float*)d_in[0];   // [8192, 64] fp32
    const float* w = (const float*)d_in[1];   // [1024, 64] fp32
    float* out = (float*)d_out;               // [8192, 1024] fp32

    // (4, 512) = 2048 blocks -> 8 blocks/CU over kernel, 4 resident
    cdist_l1_f32p_kernel<<<dim3(Mm / 256, Nn / NR), dim3(256), 0, stream>>>(
        x, w, out);
}